// Round 6
// baseline (223.350 us; speedup 1.0000x reference)
//
#include <hip/hip_runtime.h>
#include <math.h>

#define NB 4096     // B
#define NPAIR 2048  // blocks: 2 batches per block (cross-batch pipeline)
#define LL 200      // L
#define EE 50       // E
#define LP 201      // padded words per feature row (odd stride -> cheap banks)
#define NT 512      // threads per block (8 waves)
#define GG 8        // lanes per feature group
#define IT 25       // ceil(LL/GG) items held in registers per lane
#define SW 8        // small-set threshold (survivor buffer width)
#define PF 10       // prefetch iters: ceil(LL*(EE/2)/NT)

// monotonic float -> sortable uint32 (order-preserving bijection)
__device__ __forceinline__ unsigned f2key(float f) {
    unsigned b = __float_as_uint(f);
    unsigned mask = (b & 0x80000000u) ? 0xFFFFFFFFu : 0x80000000u;
    return b ^ mask;
}
__device__ __forceinline__ float key2f(unsigned kk) {
    unsigned mask = (kk & 0x80000000u) ? 0x80000000u : 0xFFFFFFFFu;
    return __uint_as_float(kk ^ mask);
}

extern "C" __global__ void __launch_bounds__(NT, 6)
rec_fused(const float* __restrict__ emb, const float* __restrict__ ratings,
          const float* __restrict__ W1, const float* __restrict__ b1,
          const float* __restrict__ W2, const float* __restrict__ b2,
          const float* __restrict__ W3, const float* __restrict__ b3,
          const int* __restrict__ uidx, const int* __restrict__ lens,
          const int* __restrict__ midx, float* __restrict__ out)
{
    __shared__ unsigned wK[EE][LP];        // 40.2 KB transposed key tile
    __shared__ int      idxA[LL];
    __shared__ float    ratA[LL];
    __shared__ int      idxB[LL];
    __shared__ float    ratB[LL];
    __shared__ unsigned sbuf[NT/GG][SW];   // per-group median survivors
    __shared__ int      scnt[NT/GG];
    __shared__ float    u[4*EE];           // [min | max | mean | med]
    __shared__ float    x[5*EE];
    __shared__ float    h1[2*EE];
    __shared__ float    h2[EE];
    __shared__ float    wsum[NT/64];

    const int blk = blockIdx.x;
    const int bA  = blk * 2;               // first batch of the pair
    const int bB  = bA + 1;                // second batch of the pair
    const int tid = threadIdx.x;
    const int n0  = lens[bA];
    const int n1  = lens[bB];

    if (tid < NT/GG) scnt[tid] = 0;
    if (tid < n0) {                     // stage per-l scalars, both batches
        idxA[tid] = uidx[bA*LL + tid];
        ratA[tid] = ratings[bA*LL + tid];
    }
    if (tid < n1) {
        idxB[tid] = uidx[bB*LL + tid];
        ratB[tid] = ratings[bB*LL + tid];
    }
    __syncthreads();

    // ---- gather batch A: coalesced float2 row reads -> LDS key tile
    {
        const int np2 = n0 * (EE/2);
        for (int p = tid; p < np2; p += NT) {
            const int l  = p / (EE/2);
            const int e2 = p - l * (EE/2);
            const float2 ev = ((const float2*)emb)[(size_t)idxA[l] * (EE/2) + e2];
            const float  r  = ratA[l];
            wK[2*e2    ][l] = f2key(ev.x * r);
            wK[2*e2 + 1][l] = f2key(ev.y * r);
        }
    }
    __syncthreads();

    const int f = tid >> 3;   // feature id (0..63; active if < 50)
    const int g = tid & 7;    // lane within 8-lane group

    float2 pf[PF];            // batch-B prefetch staging (static-indexed only)

    for (int half = 0; half < 2; ++half) {
        const int n = (half == 0) ? n0 : n1;
        const int k = (n - 1) >> 1;      // 0-based lower-median rank

        // ---- distribute LDS -> registers; fused min/max/sum
        // (same per-lane t-order as R4 => bit-exact)
        unsigned it[IT];
        unsigned kmin = 0xFFFFFFFFu, kmax = 0u;
        float sm = 0.f;
        if (f < EE) {
            #pragma unroll
            for (int t = 0; t < IT; t++) {
                const int l = g + (t << 3);
                unsigned kk = 0xFFFFFFFFu;           // sentinel (> any real key)
                if (l < n) {
                    kk = wK[f][l];
                    kmin = min(kmin, kk);
                    kmax = max(kmax, kk);
                    sm  += key2f(kk);
                }
                it[t] = kk;
            }
            #pragma unroll
            for (int m2 = 1; m2 < GG; m2 <<= 1) {
                kmin = min(kmin, (unsigned)__shfl_xor((int)kmin, m2));
                kmax = max(kmax, (unsigned)__shfl_xor((int)kmax, m2));
                sm  += __shfl_xor(sm, m2);
            }
        }

        // ---- issue batch-B emb loads now; they complete under select+tail.
        // First use (wK write) is after the tail's last barrier -> the
        // compiler's vmcnt wait lands there, hiding the HBM latency.
        if (half == 0) {
            const int np2 = n1 * (EE/2);
            #pragma unroll
            for (int t = 0; t < PF; t++) {
                const int p = tid + t * NT;
                if (p < np2) {
                    const int l  = p / (EE/2);
                    const int e2 = p - l * (EE/2);
                    pf[t] = ((const float2*)emb)[(size_t)idxB[l] * (EE/2) + e2];
                }
            }
        }

        if (f < EE) {
            // ---- median: exact interpolation-select on sortable keys.
            // Invariant: cLO = #{x<LO} <= k < cHI = #{x<HI}; median in [LO,HI).
            unsigned LO = kmin, HI = kmax + 1u;   // finite keys: no wrap
            int cLO = 0, cHI = n;
            unsigned med = 0u;
            bool small = false;
            int pass = 0;
            for (;;) {
                if (HI - LO == 1u) { med = LO; break; }   // window collapsed
                const int w = cHI - cLO;
                if (w <= SW) { small = true; break; }
                unsigned P;
                if (pass < 8) {        // float-space interpolation pivot
                    const float vlo  = key2f(LO);
                    const float vhi  = key2f(HI - 1u);
                    const float frac = (float)(k - cLO + 1) / (float)(w + 1);
                    P = f2key(vlo + (vhi - vlo) * frac);
                } else {               // guaranteed-progress bisection
                    P = LO + ((HI - LO) >> 1);
                }
                if (P <= LO) P = LO + 1u;  // strict interior: interval shrinks
                if (P >= HI) P = HI - 1u;
                int c = 0;                 // #{x < P}; sentinels never count
                #pragma unroll
                for (int t = 0; t < IT; t++) c += (it[t] < P) ? 1 : 0;
                c += __shfl_xor(c, 1);
                c += __shfl_xor(c, 2);
                c += __shfl_xor(c, 4);
                if (c > k) { HI = P; cHI = c; }
                else       { LO = P; cLO = c; }
                pass++;
            }
            if (small) {
                const int grp = tid >> 3;   // block-wide group id (wave-local)
                const int w   = cHI - cLO;  // #survivors, <= SW
                const int r   = k - cLO;    // target rank among survivors
                #pragma unroll
                for (int t = 0; t < IT; t++) {
                    const unsigned kk = it[t];
                    if (kk >= LO && kk < HI) {
                        const int pos = atomicAdd(&scnt[grp], 1);
                        if (pos < SW) sbuf[grp][pos] = kk;
                    }
                }
                // same-wave LDS ordering: lgkmcnt waits cover aliasing reads
                const unsigned sv = (g < w) ? sbuf[grp][g] : 0xFFFFFFFFu;
                int cLess = 0, cLeq = 0;
                for (int j = 0; j < w; j++) {
                    const unsigned o = sbuf[grp][j];
                    cLess += (o <  sv) ? 1 : 0;
                    cLeq  += (o <= sv) ? 1 : 0;
                }
                unsigned cand = (g < w && cLess <= r && r < cLeq) ? sv
                                                                  : 0xFFFFFFFFu;
                #pragma unroll
                for (int m2 = 1; m2 < GG; m2 <<= 1)
                    cand = min(cand, (unsigned)__shfl_xor((int)cand, m2));
                med = cand;
            }

            if (g == 0) {
                u[f]        = key2f(kmin);
                u[EE + f]   = key2f(kmax);
                u[2*EE + f] = sm / (float)n;
                u[3*EE + f] = key2f(med);
            }
        }
        __syncthreads();

        // ---- L2 norm of u[200]: per-wave shuffle tree + tiny LDS combine
        float v2 = 0.f;
        if (tid < 4*EE) { const float t = u[tid]; v2 = t * t; }
        #pragma unroll
        for (int m2 = 1; m2 < 64; m2 <<= 1) v2 += __shfl_xor(v2, m2);
        if ((tid & 63) == 0) wsum[tid >> 6] = v2;
        __syncthreads();
        float tot = 0.f;
        #pragma unroll
        for (int wv = 0; wv < NT/64; wv++) tot += wsum[wv];
        const float inv = 1.0f / sqrtf(tot);

        // ---- x = [u/||u||, emb[movie]]
        const int bcur = bA + half;
        if (tid < 4*EE)      x[tid] = u[tid] * inv;
        else if (tid < 5*EE) x[tid] = emb[(size_t)midx[bcur] * EE + (tid - 4*EE)];
        __syncthreads();

        // ---- MLP layer 1: 100 outputs x 4 lanes each
        if (tid < 4 * (2*EE)) {
            const int o = tid >> 2, gg = tid & 3;
            float acc = 0.f;
            for (int i = gg; i < 5*EE; i += 4) acc += x[i] * W1[i*(2*EE) + o];
            acc += __shfl_xor(acc, 1);
            acc += __shfl_xor(acc, 2);
            if (gg == 0) h1[o] = fmaxf(acc + b1[o], 0.f);
        }
        __syncthreads();

        // ---- MLP layer 2: 50 outputs x 8 lanes each
        if (tid < 8 * EE) {
            const int o = tid >> 3, gg = tid & 7;
            float acc = 0.f;
            for (int i = gg; i < 2*EE; i += 8) acc += h1[i] * W2[i*EE + o];
            acc += __shfl_xor(acc, 1);
            acc += __shfl_xor(acc, 2);
            acc += __shfl_xor(acc, 4);
            if (gg == 0) h2[o] = fmaxf(acc + b2[o], 0.f);
        }
        __syncthreads();

        // ---- output: full-wave shuffle dot + sigmoid
        if (tid < 64) {
            float v = (tid < EE) ? h2[tid] * W3[tid] : 0.f;
            #pragma unroll
            for (int m2 = 1; m2 < 64; m2 <<= 1) v += __shfl_xor(v, m2);
            if (tid == 0) out[bcur] = 1.0f / (1.0f + expf(-(v + b3[0])));
        }

        // ---- rotate pipeline: commit batch-B keys into wK.
        // The MLP barriers above guarantee every wave finished reading wK.
        if (half == 0) {
            const int np2 = n1 * (EE/2);
            #pragma unroll
            for (int t = 0; t < PF; t++) {
                const int p = tid + t * NT;
                if (p < np2) {
                    const int l  = p / (EE/2);
                    const int e2 = p - l * (EE/2);
                    const float r = ratB[l];
                    wK[2*e2    ][l] = f2key(pf[t].x * r);
                    wK[2*e2 + 1][l] = f2key(pf[t].y * r);
                }
            }
            if (tid < NT/GG) scnt[tid] = 0;   // re-arm small-set counters
            __syncthreads();
        }
    }
}

extern "C" void kernel_launch(void* const* d_in, const int* in_sizes, int n_in,
                              void* d_out, int out_size, void* d_ws, size_t ws_size,
                              hipStream_t stream) {
    const float* emb     = (const float*)d_in[0];
    const float* ratings = (const float*)d_in[1];
    const float* W1      = (const float*)d_in[2];
    const float* b1      = (const float*)d_in[3];
    const float* W2      = (const float*)d_in[4];
    const float* b2      = (const float*)d_in[5];
    const float* W3      = (const float*)d_in[6];
    const float* b3      = (const float*)d_in[7];
    const int*   uidx    = (const int*)d_in[8];
    const int*   lens    = (const int*)d_in[9];
    const int*   midx    = (const int*)d_in[10];
    float* out = (float*)d_out;

    hipLaunchKernelGGL(rec_fused, dim3(NPAIR), dim3(NT), 0, stream,
                       emb, ratings, W1, b1, W2, b2, W3, b3, uidx, lens, midx, out);
}

// Round 7
// 145.090 us; speedup vs baseline: 1.5394x; 1.5394x over previous
//
#include <hip/hip_runtime.h>
#include <math.h>

#define NB 4096     // B
#define NPAIR 2048  // blocks: 2 batches per block (cross-batch pipeline)
#define LL 200      // L
#define EE 50       // E
#define LP 201      // padded words per feature row (odd stride -> cheap banks)
#define NT 512      // threads per block (8 waves)
#define GG 8        // lanes per feature group
#define IT 25       // ceil(LL/GG) items held in registers per lane
#define SW 8        // small-set threshold (survivor buffer width)
#define PF 8        // prefetch iters (16 VGPRs; covers n <= 163, rest direct)

// monotonic float -> sortable uint32 (order-preserving bijection)
__device__ __forceinline__ unsigned f2key(float f) {
    unsigned b = __float_as_uint(f);
    unsigned mask = (b & 0x80000000u) ? 0xFFFFFFFFu : 0x80000000u;
    return b ^ mask;
}
__device__ __forceinline__ float key2f(unsigned kk) {
    unsigned mask = (kk & 0x80000000u) ? 0x80000000u : 0xFFFFFFFFu;
    return __uint_as_float(kk ^ mask);
}

// LDS key tile -> registers; fused min/max/sum (t-order fixed => bit-exact)
__device__ __forceinline__ void distribute_stats(
    const unsigned (*wKt)[LP], int n, int f, int g,
    unsigned it[IT], unsigned &kmin, unsigned &kmax, float &sm)
{
    kmin = 0xFFFFFFFFu; kmax = 0u; sm = 0.f;
    #pragma unroll
    for (int t = 0; t < IT; t++) {
        const int l = g + (t << 3);
        unsigned kk = 0xFFFFFFFFu;               // sentinel (> any real key)
        if (l < n) {
            kk = wKt[f][l];
            kmin = min(kmin, kk);
            kmax = max(kmax, kk);
            sm += key2f(kk);
        }
        it[t] = kk;
    }
    #pragma unroll
    for (int m2 = 1; m2 < GG; m2 <<= 1) {
        kmin = min(kmin, (unsigned)__shfl_xor((int)kmin, m2));
        kmax = max(kmax, (unsigned)__shfl_xor((int)kmax, m2));
        sm += __shfl_xor(sm, m2);
    }
}

// exact interpolation-select (invariant: cLO=#{x<LO} <= k < cHI=#{x<HI})
__device__ __forceinline__ unsigned select_median(
    int n, int k, int g, int grp, const unsigned it[IT],
    unsigned kmin, unsigned kmax, unsigned (*sbuf)[SW], int *scnt)
{
    unsigned LO = kmin, HI = kmax + 1u;   // finite keys: no wrap
    int cLO = 0, cHI = n;
    unsigned med = 0u;
    bool small = false;
    int pass = 0;
    for (;;) {
        if (HI - LO == 1u) { med = LO; break; }   // window collapsed
        const int w = cHI - cLO;
        if (w <= SW) { small = true; break; }
        unsigned P;
        if (pass < 8) {            // float-space interpolation pivot
            const float vlo = key2f(LO);
            const float vhi = key2f(HI - 1u);
            const float frac = (float)(k - cLO + 1) / (float)(w + 1);
            P = f2key(vlo + (vhi - vlo) * frac);
        } else {                   // guaranteed-progress bisection
            P = LO + ((HI - LO) >> 1);
        }
        if (P <= LO) P = LO + 1u;  // strict interior: interval shrinks
        if (P >= HI) P = HI - 1u;
        int c = 0;                 // #{x < P}; sentinels never count
        #pragma unroll
        for (int t = 0; t < IT; t++) c += (it[t] < P) ? 1 : 0;
        c += __shfl_xor(c, 1);
        c += __shfl_xor(c, 2);
        c += __shfl_xor(c, 4);
        if (c > k) { HI = P; cHI = c; }
        else       { LO = P; cLO = c; }
        pass++;
    }
    if (small) {
        const int w = cHI - cLO;   // #survivors, <= SW
        const int r = k - cLO;     // target rank among survivors
        #pragma unroll
        for (int t = 0; t < IT; t++) {
            const unsigned kk = it[t];
            if (kk >= LO && kk < HI) {
                const int pos = atomicAdd(&scnt[grp], 1);
                if (pos < SW) sbuf[grp][pos] = kk;
            }
        }
        // same-wave LDS ordering: compiler lgkmcnt waits cover these reads
        const unsigned sv = (g < w) ? sbuf[grp][g] : 0xFFFFFFFFu;
        int cLess = 0, cLeq = 0;
        for (int j = 0; j < w; j++) {
            const unsigned o = sbuf[grp][j];
            cLess += (o <  sv) ? 1 : 0;
            cLeq  += (o <= sv) ? 1 : 0;
        }
        unsigned cand = (g < w && cLess <= r && r < cLeq) ? sv : 0xFFFFFFFFu;
        #pragma unroll
        for (int m2 = 1; m2 < GG; m2 <<= 1)
            cand = min(cand, (unsigned)__shfl_xor((int)cand, m2));
        med = cand;
    }
    return med;
}

// norm + MLP + sigmoid-out. Caller must barrier after writing u[].
__device__ __forceinline__ void norm_mlp_out(
    int tid, int bcur,
    const float* __restrict__ emb,
    const float* __restrict__ W1, const float* __restrict__ b1,
    const float* __restrict__ W2, const float* __restrict__ b2,
    const float* __restrict__ W3, const float* __restrict__ b3,
    const int* __restrict__ midx, float* __restrict__ out,
    float* u, float* x, float* h1, float* h2, float* wsum)
{
    float v2 = 0.f;
    if (tid < 4*EE) { const float t = u[tid]; v2 = t * t; }
    #pragma unroll
    for (int m2 = 1; m2 < 64; m2 <<= 1) v2 += __shfl_xor(v2, m2);
    if ((tid & 63) == 0) wsum[tid >> 6] = v2;
    __syncthreads();
    float tot = 0.f;
    #pragma unroll
    for (int wv = 0; wv < NT/64; wv++) tot += wsum[wv];
    const float inv = 1.0f / sqrtf(tot);

    if (tid < 4*EE)      x[tid] = u[tid] * inv;
    else if (tid < 5*EE) x[tid] = emb[(size_t)midx[bcur] * EE + (tid - 4*EE)];
    __syncthreads();

    if (tid < 4 * (2*EE)) {          // layer 1: 100 outputs x 4 lanes
        const int o = tid >> 2, gg = tid & 3;
        float acc = 0.f;
        for (int i = gg; i < 5*EE; i += 4) acc += x[i] * W1[i*(2*EE) + o];
        acc += __shfl_xor(acc, 1);
        acc += __shfl_xor(acc, 2);
        if (gg == 0) h1[o] = fmaxf(acc + b1[o], 0.f);
    }
    __syncthreads();

    if (tid < 8 * EE) {              // layer 2: 50 outputs x 8 lanes
        const int o = tid >> 3, gg = tid & 7;
        float acc = 0.f;
        for (int i = gg; i < 2*EE; i += 8) acc += h1[i] * W2[i*EE + o];
        acc += __shfl_xor(acc, 1);
        acc += __shfl_xor(acc, 2);
        acc += __shfl_xor(acc, 4);
        if (gg == 0) h2[o] = fmaxf(acc + b2[o], 0.f);
    }
    __syncthreads();

    if (tid < 64) {                  // output: full-wave shuffle dot
        float v = (tid < EE) ? h2[tid] * W3[tid] : 0.f;
        #pragma unroll
        for (int m2 = 1; m2 < 64; m2 <<= 1) v += __shfl_xor(v, m2);
        if (tid == 0) out[bcur] = 1.0f / (1.0f + expf(-(v + b3[0])));
    }
}

extern "C" __global__ void __launch_bounds__(NT, 6)
rec_fused(const float* __restrict__ emb, const float* __restrict__ ratings,
          const float* __restrict__ W1, const float* __restrict__ b1,
          const float* __restrict__ W2, const float* __restrict__ b2,
          const float* __restrict__ W3, const float* __restrict__ b3,
          const int* __restrict__ uidx, const int* __restrict__ lens,
          const int* __restrict__ midx, float* __restrict__ out)
{
    __shared__ unsigned wK[EE][LP];        // 40.2 KB transposed key tile
    __shared__ int      idxA[LL];
    __shared__ float    ratA[LL];
    __shared__ int      idxB[LL];
    __shared__ float    ratB[LL];
    __shared__ unsigned sbuf[NT/GG][SW];   // per-group median survivors
    __shared__ int      scnt[NT/GG];
    __shared__ float    u[4*EE];           // [min | max | mean | med]
    __shared__ float    x[5*EE];
    __shared__ float    h1[2*EE];
    __shared__ float    h2[EE];
    __shared__ float    wsum[NT/64];

    const int blk = blockIdx.x;
    const int bA  = blk * 2;
    const int bB  = bA + 1;
    const int tid = threadIdx.x;
    const int n0  = lens[bA];
    const int n1  = lens[bB];
    const int f   = tid >> 3;   // feature id (0..63; active if < 50)
    const int g   = tid & 7;    // lane within 8-lane group

    if (tid < NT/GG) scnt[tid] = 0;
    if (tid < n0) {                     // stage per-l scalars, both batches
        idxA[tid] = uidx[bA*LL + tid];
        ratA[tid] = ratings[bA*LL + tid];
    }
    if (tid < n1) {
        idxB[tid] = uidx[bB*LL + tid];
        ratB[tid] = ratings[bB*LL + tid];
    }
    __syncthreads();

    // ---- gather batch A: coalesced float2 row reads -> LDS key tile
    {
        const int np2 = n0 * (EE/2);
        for (int p = tid; p < np2; p += NT) {
            const int l  = p / (EE/2);
            const int e2 = p - l * (EE/2);
            const float2 ev = ((const float2*)emb)[(size_t)idxA[l] * (EE/2) + e2];
            const float  r  = ratA[l];
            wK[2*e2    ][l] = f2key(ev.x * r);
            wK[2*e2 + 1][l] = f2key(ev.y * r);
        }
    }
    __syncthreads();

    // ================= batch A =================
    unsigned it[IT];
    unsigned kmin = 0xFFFFFFFFu, kmax = 0u;
    float sm = 0.f;
    if (f < EE) distribute_stats(wK, n0, f, g, it, kmin, kmax, sm);
    __syncthreads();                       // all wK reads done: tile is free

    // ---- prefetch batch B into registers (straight-line, short live range:
    // dies at the commit below, before any barrier)
    const int np2B = n1 * (EE/2);
    float2 pf[PF];
    #pragma unroll
    for (int t = 0; t < PF; t++) {
        const int p = tid + t * NT;
        pf[t] = make_float2(0.f, 0.f);
        if (p < np2B) {
            const int l  = p / (EE/2);
            const int e2 = p - l * (EE/2);
            pf[t] = ((const float2*)emb)[(size_t)idxB[l] * (EE/2) + e2];
        }
    }

    // ---- select A runs on registers while the pf loads are in flight
    if (f < EE) {
        const int k0 = (n0 - 1) >> 1;
        const unsigned med = select_median(n0, k0, g, f, it, kmin, kmax,
                                           sbuf, scnt);
        if (g == 0) {
            u[f]        = key2f(kmin);
            u[EE + f]   = key2f(kmax);
            u[2*EE + f] = sm / (float)n0;
            u[3*EE + f] = key2f(med);
        }
    }

    // ---- commit batch-B keys (vmcnt waits land here, latency mostly hidden)
    #pragma unroll
    for (int t = 0; t < PF; t++) {
        const int p = tid + t * NT;
        if (p < np2B) {
            const int l  = p / (EE/2);
            const int e2 = p - l * (EE/2);
            const float r = ratB[l];
            wK[2*e2    ][l] = f2key(pf[t].x * r);
            wK[2*e2 + 1][l] = f2key(pf[t].y * r);
        }
    }
    for (int p = tid + PF*NT; p < np2B; p += NT) {   // n1 > 163 residual
        const int l  = p / (EE/2);
        const int e2 = p - l * (EE/2);
        const float2 ev = ((const float2*)emb)[(size_t)idxB[l] * (EE/2) + e2];
        const float  r  = ratB[l];
        wK[2*e2    ][l] = f2key(ev.x * r);
        wK[2*e2 + 1][l] = f2key(ev.y * r);
    }
    __syncthreads();                       // u[] ready; wK committed
    if (tid < NT/GG) scnt[tid] = 0;        // re-arm (tail barriers order this
                                           // before batch-B's atomics)

    norm_mlp_out(tid, bA, emb, W1, b1, W2, b2, W3, b3, midx, out,
                 u, x, h1, h2, wsum);
    __syncthreads();                       // tail done; u/x/h reusable

    // ================= batch B =================
    if (f < EE) {
        distribute_stats(wK, n1, f, g, it, kmin, kmax, sm);
        const int k1 = (n1 - 1) >> 1;
        const unsigned med = select_median(n1, k1, g, f, it, kmin, kmax,
                                           sbuf, scnt);
        if (g == 0) {
            u[f]        = key2f(kmin);
            u[EE + f]   = key2f(kmax);
            u[2*EE + f] = sm / (float)n1;
            u[3*EE + f] = key2f(med);
        }
    }
    __syncthreads();

    norm_mlp_out(tid, bB, emb, W1, b1, W2, b2, W3, b3, midx, out,
                 u, x, h1, h2, wsum);
}

extern "C" void kernel_launch(void* const* d_in, const int* in_sizes, int n_in,
                              void* d_out, int out_size, void* d_ws, size_t ws_size,
                              hipStream_t stream) {
    const float* emb     = (const float*)d_in[0];
    const float* ratings = (const float*)d_in[1];
    const float* W1      = (const float*)d_in[2];
    const float* b1      = (const float*)d_in[3];
    const float* W2      = (const float*)d_in[4];
    const float* b2      = (const float*)d_in[5];
    const float* W3      = (const float*)d_in[6];
    const float* b3      = (const float*)d_in[7];
    const int*   uidx    = (const int*)d_in[8];
    const int*   lens    = (const int*)d_in[9];
    const int*   midx    = (const int*)d_in[10];
    float* out = (float*)d_out;

    hipLaunchKernelGGL(rec_fused, dim3(NPAIR), dim3(NT), 0, stream,
                       emb, ratings, W1, b1, W2, b2, W3, b3, uidx, lens, midx, out);
}

// Round 8
// 93.460 us; speedup vs baseline: 2.3898x; 1.5524x over previous
//
#include <hip/hip_runtime.h>
#include <math.h>

#define NB 4096     // B
#define LL 200      // L
#define EE 50       // E
#define CH 104      // gather chunk-1 length (13*8); chunk-2 = 96
#define CP 105      // chunk tile stride in words (odd -> spread banks)
#define NT 512      // k1 threads (8 waves)
#define GG 8        // lanes per feature group
#define IT 25       // items per lane in registers
#define IT1 13      // chunk-1 covers t in [0,13), l = g+8t < 104
#define SW 8        // small-set threshold

#define K2B 256     // k2 blocks
#define K2T 512     // k2 threads (8 waves)
#define BPB 16      // batches per k2 block (2 reps x 8 waves)

// monotonic float -> sortable uint32 (order-preserving bijection)
__device__ __forceinline__ unsigned f2key(float f) {
    unsigned b = __float_as_uint(f);
    unsigned mask = (b & 0x80000000u) ? 0xFFFFFFFFu : 0x80000000u;
    return b ^ mask;
}
__device__ __forceinline__ float key2f(unsigned kk) {
    unsigned mask = (kk & 0x80000000u) ? 0x80000000u : 0xFFFFFFFFu;
    return __uint_as_float(kk ^ mask);
}

// exact interpolation-select (invariant: cLO=#{x<LO} <= k < cHI=#{x<HI})
__device__ __forceinline__ unsigned select_median(
    int n, int k, int g, int grp, const unsigned it[IT],
    unsigned kmin, unsigned kmax, unsigned (*sbuf)[SW], int *scnt)
{
    unsigned LO = kmin, HI = kmax + 1u;   // finite keys: no wrap
    int cLO = 0, cHI = n;
    unsigned med = 0u;
    bool small = false;
    int pass = 0;
    for (;;) {
        if (HI - LO == 1u) { med = LO; break; }   // window collapsed
        const int w = cHI - cLO;
        if (w <= SW) { small = true; break; }
        unsigned P;
        if (pass < 8) {            // float-space interpolation pivot
            const float vlo = key2f(LO);
            const float vhi = key2f(HI - 1u);
            const float frac = (float)(k - cLO + 1) / (float)(w + 1);
            P = f2key(vlo + (vhi - vlo) * frac);
        } else {                   // guaranteed-progress bisection
            P = LO + ((HI - LO) >> 1);
        }
        if (P <= LO) P = LO + 1u;  // strict interior: interval shrinks
        if (P >= HI) P = HI - 1u;
        int c = 0;                 // #{x < P}; sentinels never count
        #pragma unroll
        for (int t = 0; t < IT; t++) c += (it[t] < P) ? 1 : 0;
        c += __shfl_xor(c, 1);
        c += __shfl_xor(c, 2);
        c += __shfl_xor(c, 4);
        if (c > k) { HI = P; cHI = c; }
        else       { LO = P; cLO = c; }
        pass++;
    }
    if (small) {
        const int w = cHI - cLO;   // #survivors, <= SW
        const int r = k - cLO;     // target rank among survivors
        #pragma unroll
        for (int t = 0; t < IT; t++) {
            const unsigned kk = it[t];
            if (kk >= LO && kk < HI) {
                const int pos = atomicAdd(&scnt[grp], 1);
                if (pos < SW) sbuf[grp][pos] = kk;
            }
        }
        // same-wave LDS ordering: compiler lgkmcnt waits cover these reads
        const unsigned sv = (g < w) ? sbuf[grp][g] : 0xFFFFFFFFu;
        int cLess = 0, cLeq = 0;
        for (int j = 0; j < w; j++) {
            const unsigned o = sbuf[grp][j];
            cLess += (o <  sv) ? 1 : 0;
            cLeq  += (o <= sv) ? 1 : 0;
        }
        unsigned cand = (g < w && cLess <= r && r < cLeq) ? sv : 0xFFFFFFFFu;
        #pragma unroll
        for (int m2 = 1; m2 < GG; m2 <<= 1)
            cand = min(cand, (unsigned)__shfl_xor((int)cand, m2));
        med = cand;
    }
    return med;
}

// ================= kernel 1: pooled stats -> workspace =================
extern "C" __global__ void __launch_bounds__(NT, 8)
rec_stats(const float* __restrict__ emb, const float* __restrict__ ratings,
          const int* __restrict__ uidx, const int* __restrict__ lens,
          float* __restrict__ uo)
{
    __shared__ unsigned wK[EE][CP];     // 21 KB chunked key tile
    __shared__ int      idxL[LL];
    __shared__ float    ratL[LL];
    __shared__ unsigned sbuf[EE][SW];
    __shared__ int      scnt[EE];

    const int b   = blockIdx.x;
    const int tid = threadIdx.x;
    const int n   = lens[b];
    const int k   = (n - 1) >> 1;

    if (tid < EE) scnt[tid] = 0;
    if (tid < n) {
        idxL[tid] = uidx[b*LL + tid];
        ratL[tid] = ratings[b*LL + tid];
    }
    __syncthreads();

    const int f = tid >> 3;   // feature id (0..63; active if < 50)
    const int g = tid & 7;

    // ---- gather chunk 1: l in [0, min(n,CH))
    const int c1 = (n < CH) ? n : CH;
    for (int p = tid; p < c1*(EE/2); p += NT) {
        const int l  = p / (EE/2);
        const int e2 = p - l*(EE/2);
        const float2 ev = ((const float2*)emb)[(size_t)idxL[l]*(EE/2) + e2];
        const float  r  = ratL[l];
        wK[2*e2    ][l] = f2key(ev.x * r);
        wK[2*e2 + 1][l] = f2key(ev.y * r);
    }
    __syncthreads();

    // ---- distribute chunk 1 (t-order identical to R4 => bit-exact stats)
    unsigned it[IT];
    unsigned kmin = 0xFFFFFFFFu, kmax = 0u;
    float sm = 0.f;
    if (f < EE) {
        #pragma unroll
        for (int t = 0; t < IT1; t++) {
            const int l = g + (t << 3);
            unsigned kk = 0xFFFFFFFFu;
            if (l < n) {
                kk = wK[f][l];
                kmin = min(kmin, kk); kmax = max(kmax, kk); sm += key2f(kk);
            }
            it[t] = kk;
        }
    }
    __syncthreads();          // chunk-1 reads done; tile reusable

    // ---- gather chunk 2: l in [CH, n)
    const int c2 = n - CH;    // may be <= 0
    for (int p = tid; p < c2*(EE/2); p += NT) {
        const int col = p / (EE/2);
        const int e2  = p - col*(EE/2);
        const int l   = CH + col;
        const float2 ev = ((const float2*)emb)[(size_t)idxL[l]*(EE/2) + e2];
        const float  r  = ratL[l];
        wK[2*e2    ][col] = f2key(ev.x * r);
        wK[2*e2 + 1][col] = f2key(ev.y * r);
    }
    __syncthreads();

    if (f < EE) {
        #pragma unroll
        for (int t = IT1; t < IT; t++) {
            const int l = g + (t << 3);
            unsigned kk = 0xFFFFFFFFu;
            if (l < n) {
                kk = wK[f][l - CH];
                kmin = min(kmin, kk); kmax = max(kmax, kk); sm += key2f(kk);
            }
            it[t] = kk;
        }
        #pragma unroll
        for (int m2 = 1; m2 < GG; m2 <<= 1) {
            kmin = min(kmin, (unsigned)__shfl_xor((int)kmin, m2));
            kmax = max(kmax, (unsigned)__shfl_xor((int)kmax, m2));
            sm  += __shfl_xor(sm, m2);
        }

        const unsigned med = select_median(n, k, g, f, it, kmin, kmax,
                                           sbuf, scnt);
        if (g == 0) {
            float* ub = uo + (size_t)b * (4*EE);
            ub[f]        = key2f(kmin);
            ub[EE + f]   = key2f(kmax);
            ub[2*EE + f] = sm / (float)n;
            ub[3*EE + f] = key2f(med);
        }
    }
}

// ================= kernel 2: norm + MLP (weights in LDS) =================
extern "C" __global__ void __launch_bounds__(K2T, 2)
rec_mlp(const float* __restrict__ emb,
        const float* __restrict__ W1, const float* __restrict__ b1,
        const float* __restrict__ W2, const float* __restrict__ b2,
        const float* __restrict__ W3, const float* __restrict__ b3,
        const int* __restrict__ midx, const float* __restrict__ uo,
        float* __restrict__ out)
{
    __shared__ float W1s[5*EE * 2*EE];   // 100 KB
    __shared__ float W2s[2*EE * EE];     // 20 KB
    __shared__ float b1s[2*EE];
    __shared__ float b2s[EE];
    __shared__ float W3s[EE];
    __shared__ float xs[8][252];         // per-wave x / h1 scratch

    const int tid = threadIdx.x;

    // ---- stage weights once per block (float2 coalesced)
    for (int p = tid; p < (5*EE*2*EE)/2; p += K2T)
        ((float2*)W1s)[p] = ((const float2*)W1)[p];
    for (int p = tid; p < (2*EE*EE)/2; p += K2T)
        ((float2*)W2s)[p] = ((const float2*)W2)[p];
    if (tid < 2*EE) b1s[tid] = b1[tid];
    if (tid < EE)   { b2s[tid] = b2[tid]; W3s[tid] = W3[tid]; }
    __syncthreads();
    const float bias3 = b3[0];

    const int w    = tid >> 6;
    const int lane = tid & 63;

    #pragma unroll
    for (int rep = 0; rep < 2; rep++) {
        const int b = blockIdx.x * BPB + rep * 8 + w;

        // ---- load u row (coalesced), L2-norm via wave shuffle tree
        float uv0 = 0.f, uv1 = 0.f, uv2 = 0.f, uv3 = 0.f;
        const float* ub = uo + (size_t)b * (4*EE);
        uv0 = ub[lane];
        uv1 = ub[lane + 64];
        uv2 = ub[lane + 128];
        if (lane < 4*EE - 192) uv3 = ub[lane + 192];
        float v2 = uv0*uv0 + uv1*uv1 + uv2*uv2 + uv3*uv3;
        #pragma unroll
        for (int m2 = 1; m2 < 64; m2 <<= 1) v2 += __shfl_xor(v2, m2);
        const float inv = 1.0f / sqrtf(v2);

        // ---- x = [u/||u||, emb[movie]] into this wave's LDS row
        xs[w][lane]       = uv0 * inv;
        xs[w][lane + 64]  = uv1 * inv;
        xs[w][lane + 128] = uv2 * inv;
        if (lane < 4*EE - 192) xs[w][lane + 192] = uv3 * inv;
        if (lane < EE) xs[w][4*EE + lane] = emb[(size_t)midx[b]*EE + lane];
        asm volatile("s_waitcnt lgkmcnt(0)" ::: "memory");  // wave-local RAW

        // ---- layer 1: lane owns outputs o=lane and (lane<36) o+64
        const int o2 = (lane + 64 < 2*EE) ? lane + 64 : 2*EE - 1;
        float a0 = 0.f, a1 = 0.f;
        #pragma unroll 5
        for (int i = 0; i < 5*EE; i++) {
            const float xv = xs[w][i];              // LDS broadcast
            a0 += xv * W1s[i*(2*EE) + lane];
            a1 += xv * W1s[i*(2*EE) + o2];
        }
        const float h0  = fmaxf(a0 + b1s[lane], 0.f);
        const float h64 = fmaxf(a1 + b1s[o2],   0.f);
        // h1 -> reuse xs row (x is dead; same-wave ordering via waitcnt)
        xs[w][lane] = h0;
        if (lane < 2*EE - 64) xs[w][lane + 64] = h64;
        asm volatile("s_waitcnt lgkmcnt(0)" ::: "memory");

        // ---- layer 2 + output dot
        const int oc = (lane < EE) ? lane : EE - 1;
        float a2 = 0.f;
        #pragma unroll 5
        for (int i = 0; i < 2*EE; i++)
            a2 += xs[w][i] * W2s[i*EE + oc];
        const float h2v = fmaxf(a2 + b2s[oc], 0.f);
        float v = (lane < EE) ? h2v * W3s[lane] : 0.f;
        #pragma unroll
        for (int m2 = 1; m2 < 64; m2 <<= 1) v += __shfl_xor(v, m2);
        if (lane == 0) out[b] = 1.0f / (1.0f + expf(-(v + bias3)));
    }
}

extern "C" void kernel_launch(void* const* d_in, const int* in_sizes, int n_in,
                              void* d_out, int out_size, void* d_ws, size_t ws_size,
                              hipStream_t stream) {
    const float* emb     = (const float*)d_in[0];
    const float* ratings = (const float*)d_in[1];
    const float* W1      = (const float*)d_in[2];
    const float* b1      = (const float*)d_in[3];
    const float* W2      = (const float*)d_in[4];
    const float* b2      = (const float*)d_in[5];
    const float* W3      = (const float*)d_in[6];
    const float* b3      = (const float*)d_in[7];
    const int*   uidx    = (const int*)d_in[8];
    const int*   lens    = (const int*)d_in[9];
    const int*   midx    = (const int*)d_in[10];
    float* out = (float*)d_out;
    float* uo  = (float*)d_ws;          // 4096*200*4 = 3.28 MB raw stats

    hipLaunchKernelGGL(rec_stats, dim3(NB), dim3(NT), 0, stream,
                       emb, ratings, uidx, lens, uo);
    hipLaunchKernelGGL(rec_mlp, dim3(K2B), dim3(K2T), 0, stream,
                       emb, W1, b1, W2, b2, W3, b3, midx, uo, out);
}